// Round 1
// baseline (264.110 us; speedup 1.0000x reference)
//
#include <hip/hip_runtime.h>

#define KW 11          // window size
#define PAD 5
#define TW 32          // output tile width
#define TH 32          // output tile height
#define IW (TW + KW - 1)   // 42 input cols
#define IH (TH + KW - 1)   // 42 input rows
#define IPITCH (IW + 2)    // 44 — keeps rows stride-1, <=2-way bank aliasing (free)
#define HPITCH (TW + 1)    // 33
#define IMH 512
#define IMW 512

__global__ __launch_bounds__(256) void ssim_main(
    const float* __restrict__ img1, const float* __restrict__ img2,
    const float* __restrict__ window, double* __restrict__ acc)
{
    __shared__ float s1[IH * IPITCH];
    __shared__ float s2[IH * IPITCH];
    __shared__ float h1[IH * HPITCH];
    __shared__ float h2[IH * HPITCH];
    __shared__ float h11[IH * HPITCH];
    __shared__ float h22[IH * HPITCH];
    __shared__ float h12[IH * HPITCH];
    __shared__ float g[KW];
    __shared__ float wsum[4];

    const int t = threadIdx.x;

    // Recover separable 1D Gaussian: row-sums of the 2D window (columns sum to 1).
    // window layout (K, K, 1, C) -> flat ((i*K + j)*1)*3 + c ; channels identical.
    if (t < KW) {
        float s = 0.f;
        for (int j = 0; j < KW; ++j) s += window[(t * KW + j) * 3];
        g[t] = s;
    }

    const int plane = blockIdx.z;                 // n*C + c, 48 planes
    const size_t base = (size_t)plane * IMH * IMW;
    const int ox0 = blockIdx.x * TW;
    const int oy0 = blockIdx.y * TH;
    const int ix0 = ox0 - PAD;
    const int iy0 = oy0 - PAD;

    // Stage input tiles (with zero padding at image borders) into LDS.
    for (int idx = t; idx < IH * IW; idx += 256) {
        int r = idx / IW, c = idx - r * IW;
        int gr = iy0 + r, gc = ix0 + c;
        float v1 = 0.f, v2 = 0.f;
        if (gr >= 0 && gr < IMH && gc >= 0 && gc < IMW) {
            size_t o = base + (size_t)gr * IMW + gc;
            v1 = img1[o];
            v2 = img2[o];
        }
        s1[r * IPITCH + c] = v1;
        s2[r * IPITCH + c] = v2;
    }
    __syncthreads();

    // Horizontal 11-tap pass: 5 moment images, rows 0..41, cols 0..31.
    for (int idx = t; idx < IH * TW; idx += 256) {
        int r = idx / TW, c = idx - r * TW;
        const float* p1 = &s1[r * IPITCH + c];
        const float* p2 = &s2[r * IPITCH + c];
        float a1 = 0.f, a2 = 0.f, a11 = 0.f, a22 = 0.f, a12 = 0.f;
#pragma unroll
        for (int j = 0; j < KW; ++j) {
            float w = g[j];
            float x1 = p1[j];
            float x2 = p2[j];
            a1  += w * x1;
            a2  += w * x2;
            a11 += w * x1 * x1;
            a22 += w * x2 * x2;
            a12 += w * x1 * x2;
        }
        int o = r * HPITCH + c;
        h1[o] = a1; h2[o] = a2; h11[o] = a11; h22[o] = a22; h12[o] = a12;
    }
    __syncthreads();

    // Vertical 11-tap pass + SSIM map + local accumulation.
    const float C1v = 0.0001f;   // 0.01^2
    const float C2v = 0.0009f;   // 0.03^2
    float lsum = 0.f;
    for (int idx = t; idx < TH * TW; idx += 256) {
        int r = idx / TW, c = idx - r * TW;
        float mu1 = 0.f, mu2 = 0.f, m11 = 0.f, m22 = 0.f, m12 = 0.f;
#pragma unroll
        for (int i = 0; i < KW; ++i) {
            float w = g[i];
            int o = (r + i) * HPITCH + c;
            mu1 += w * h1[o];
            mu2 += w * h2[o];
            m11 += w * h11[o];
            m22 += w * h22[o];
            m12 += w * h12[o];
        }
        float mu1sq = mu1 * mu1;
        float mu2sq = mu2 * mu2;
        float mu12  = mu1 * mu2;
        float sig1  = m11 - mu1sq;
        float sig2  = m22 - mu2sq;
        float sig12 = m12 - mu12;
        float num = (2.f * mu12 + C1v) * (2.f * sig12 + C2v);
        float den = (mu1sq + mu2sq + C1v) * (sig1 + sig2 + C2v);
        lsum += num / den;
    }

    // Wave (64-lane) shuffle reduction, then cross-wave via LDS.
#pragma unroll
    for (int off = 32; off > 0; off >>= 1) lsum += __shfl_down(lsum, off, 64);
    if ((t & 63) == 0) wsum[t >> 6] = lsum;
    __syncthreads();
    if (t == 0) {
        float b = wsum[0] + wsum[1] + wsum[2] + wsum[3];
        atomicAdd(acc, (double)b);
    }
}

__global__ void zero_acc(double* acc) { *acc = 0.0; }

__global__ void finalize(const double* __restrict__ acc, float* __restrict__ out,
                         double inv_n) {
    out[0] = (float)(*acc * inv_n);
}

extern "C" void kernel_launch(void* const* d_in, const int* in_sizes, int n_in,
                              void* d_out, int out_size, void* d_ws, size_t ws_size,
                              hipStream_t stream) {
    const float* img1   = (const float*)d_in[0];
    const float* img2   = (const float*)d_in[1];
    const float* window = (const float*)d_in[2];
    float* out = (float*)d_out;
    double* acc = (double*)d_ws;

    const int nplanes = in_sizes[0] / (IMH * IMW);   // 16*3 = 48
    const long long total = (long long)in_sizes[0];

    zero_acc<<<1, 1, 0, stream>>>(acc);
    dim3 grid(IMW / TW, IMH / TH, nplanes);          // 16 x 16 x 48
    ssim_main<<<grid, 256, 0, stream>>>(img1, img2, window, acc);
    finalize<<<1, 1, 0, stream>>>(acc, out, 1.0 / (double)total);
}